// Round 5
// baseline (26.513 us; speedup 1.0000x reference)
//
#include <hip/hip_runtime.h>

// REM generator: out[h][i][j], 8 x 2048 x 2048 f32.
// out[h][i][j] = V_h[i-j] for i>=j else 0, -eye baked into V_h[0];
//   V_h[d] = (d % n == 0) ? F[Lc(d)] * G[Lc(d/n)] : 0,  Lc(x) = (x<=200)?x:0.
// Persistent blocks: 256 blocks = 1/CU, each owns 64 rows of one head.
// Prologue (cheap exp2f table build + phase-split reversed windows) paid ONCE
// per CU, then a pure store stream: conflict-free ds_read_b128 + dwordx4 store.

#define CAP  200
#define T    2048
#define ROWS 64    // 2048/64 = 32 blocks per head x 8 heads = 256 blocks = 1/CU

typedef float f32x4 __attribute__((ext_vector_type(4)));

__device__ __forceinline__ float powL(float c /*log2|base|*/, bool neg, int L) {
    // base^L for integer L>=0: exact 1 at L==0 (covers base==0 -> c==-inf)
    if (L == 0) return 1.0f;
    float v = exp2f((float)L * c);
    return (neg && (L & 1)) ? -v : v;
}

__global__ __launch_bounds__(256) void rem_kernel(
    const float* __restrict__ eta,
    const float* __restrict__ nu,
    const float* __restrict__ theta,
    f32x4* __restrict__ out4)
{
    __shared__ float V[T];           // 8 KB
    __shared__ f32x4 R[4 * 512];     // 32 KB

    const int h    = blockIdx.y;
    const int row0 = blockIdx.x * ROWS;
    const int tid  = threadIdx.x;

    // ---- per-head scalars (one log2f instead of per-entry powf) ----
    float cA = 0.0f, th = 0.0f;
    bool  neg = false;
    if (h < 3) {
        float lam = tanhf(eta[h]);
        cA = log2f(fabsf(lam));
        neg = (lam < 0.0f);
    } else if (h < 6) {
        float gm = 1.0f / (1.0f + expf(-nu[h - 3]));
        cA = log2f(gm);
        th = theta[h - 3];
    } else {
        th = theta[h - 3];           // h6 -> theta[3], h7 -> theta[4]
    }

    // ---- stage 1: V[k] (8 entries/thread, ~1-2 TRANS each) ----
    for (int k = tid; k < T; k += 256) {
        const int Lk = (k <= CAP) ? k : 0;
        float val;
        switch (h) {
        case 0: case 1:
            val = powL(cA, neg, Lk);
            break;
        case 2: {                                  // dilate(lam2^L, 4)
            if (k & 3) { val = 0.0f; }
            else { int q = k >> 2; int Lq = (q <= CAP) ? q : 0;
                   val = powL(cA, neg, Lq); }
        } break;
        case 3: case 4:                            // gam^L * cos(theta*L)
            val = powL(cA, false, Lk) * cosf(th * (float)Lk);
            break;
        case 5:                                    // gam2^L * sin(theta2*L)
            val = powL(cA, false, Lk) * sinf(th * (float)Lk);
            break;
        case 6: {                                  // dilate(cos,3) * cos
            unsigned q = (unsigned)k / 3u;
            if ((unsigned)k != 3u * q) { val = 0.0f; }
            else { int Lq = ((int)q <= CAP) ? (int)q : 0;
                   val = cosf(th * (float)Lk) * cosf(th * (float)Lq); }
        } break;
        default: {                                 // dilate(sin,2) * sin
            if (k & 1) { val = 0.0f; }
            else { int q = k >> 1; int Lq = (q <= CAP) ? q : 0;
                   val = sinf(th * (float)Lk) * sinf(th * (float)Lq); }
        } break;
        }
        if (k == 0) val -= 1.0f;                   // bake -eye into V[0]
        V[k] = val;
    }
    __syncthreads();

    // ---- stage 2: R[p][m] = {V[4m+p], V[4m+p-1], V[4m+p-2], V[4m+p-3]} ----
    const f32x4* V4 = reinterpret_cast<const f32x4*>(V);
    #pragma unroll
    for (int it = 0; it < 8; ++it) {
        const int p = it >> 1;                     // compile-time phase
        const int m = ((it & 1) << 8) + tid;       // 0..511
        f32x4 A = V4[m];
        f32x4 B = (m > 0) ? V4[m - 1] : (f32x4){0.f, 0.f, 0.f, 0.f};
        f32x4 w;
        if      (p == 0) w = (f32x4){A.x, B.w, B.z, B.y};
        else if (p == 1) w = (f32x4){A.y, A.x, B.w, B.z};
        else if (p == 2) w = (f32x4){A.z, A.y, A.x, B.w};
        else             w = (f32x4){A.w, A.z, A.y, A.x};
        R[p * 512 + m] = w;
    }
    __syncthreads();

    // ---- stage 3: store stream (1 b128 LDS read + 1 dwordx4 store per f4) ----
    f32x4* outh = out4 + (size_t)h * (T * 512);
    const f32x4 zero = {0.f, 0.f, 0.f, 0.f};
    #pragma unroll 8
    for (int k2 = 0; k2 < ROWS * 2; ++k2) {
        const int r  = k2 >> 1;
        const int c4 = ((k2 & 1) << 8) + tid;
        const int i  = row0 + r;
        const int p  = i & 3;                      // wave-uniform
        const int m  = (i >> 2) - c4;              // lane stride -1: conflict-free
        f32x4 t = R[p * 512 + ((m > 0) ? m : 0)];
        if (m < 0) t = zero;
        outh[(size_t)i * 512 + c4] = t;
    }
}

extern "C" void kernel_launch(void* const* d_in, const int* in_sizes, int n_in,
                              void* d_out, int out_size, void* d_ws, size_t ws_size,
                              hipStream_t stream) {
    (void)in_sizes; (void)n_in; (void)d_ws; (void)ws_size; (void)out_size;
    const float* eta   = (const float*)d_in[0];
    const float* nu    = (const float*)d_in[1];
    const float* theta = (const float*)d_in[2];

    dim3 grid(T / ROWS, 8, 1);   // 32 x 8 = 256 blocks -> 1 per CU (persistent)
    rem_kernel<<<grid, 256, 0, stream>>>(eta, nu, theta, (f32x4*)d_out);
}

// Round 6
// 26.011 us; speedup vs baseline: 1.0193x; 1.0193x over previous
//
#include <hip/hip_runtime.h>

// REM generator: out[h][i][j], 8 x 2048 x 2048 f32.
// out[h][i][j] = V_h[i-j] for i>=j else 0, -eye baked into V_h[0];
//   V_h[d] = (d % n == 0) ? F[Lc(d)] * G[Lc(d/n)] : 0,  Lc(x) = (x<=200)?x:0.
// Best measured geometry (R4): 1024 blocks (4/CU, 16 waves/CU).
// Cheap exp2f table build -> phase-split reversed float4 windows in LDS ->
// store stream: one conflict-free ds_read_b128 + one dwordx4 store per f4.
// Measured floor: 134.2 MB write @ ~6.6 TB/s + ~5 us fixed harness overhead.

#define CAP  200
#define T    2048
#define ROWS 16

typedef float f32x4 __attribute__((ext_vector_type(4)));

__device__ __forceinline__ float powL(float c /*log2|base|*/, bool neg, int L) {
    // base^L for integer L>=0: exact 1 at L==0 (covers base==0 -> c==-inf)
    if (L == 0) return 1.0f;
    float v = exp2f((float)L * c);
    return (neg && (L & 1)) ? -v : v;
}

__global__ __launch_bounds__(256) void rem_kernel(
    const float* __restrict__ eta,
    const float* __restrict__ nu,
    const float* __restrict__ theta,
    f32x4* __restrict__ out4)
{
    __shared__ float V[T];           // 8 KB
    __shared__ f32x4 R[4 * 512];     // 32 KB

    const int h    = blockIdx.y;
    const int row0 = blockIdx.x * ROWS;
    const int tid  = threadIdx.x;

    // ---- per-head scalars (one log2f instead of per-entry powf) ----
    float cA = 0.0f, th = 0.0f;
    bool  neg = false;
    if (h < 3) {
        float lam = tanhf(eta[h]);
        cA = log2f(fabsf(lam));
        neg = (lam < 0.0f);
    } else if (h < 6) {
        float gm = 1.0f / (1.0f + expf(-nu[h - 3]));
        cA = log2f(gm);
        th = theta[h - 3];
    } else {
        th = theta[h - 3];           // h6 -> theta[3], h7 -> theta[4]
    }

    // ---- stage 1: V[k] (8 entries/thread) ----
    for (int k = tid; k < T; k += 256) {
        const int Lk = (k <= CAP) ? k : 0;
        float val;
        switch (h) {
        case 0: case 1:
            val = powL(cA, neg, Lk);
            break;
        case 2: {                                  // dilate(lam2^L, 4)
            if (k & 3) { val = 0.0f; }
            else { int q = k >> 2; int Lq = (q <= CAP) ? q : 0;
                   val = powL(cA, neg, Lq); }
        } break;
        case 3: case 4:                            // gam^L * cos(theta*L)
            val = powL(cA, false, Lk) * cosf(th * (float)Lk);
            break;
        case 5:                                    // gam2^L * sin(theta2*L)
            val = powL(cA, false, Lk) * sinf(th * (float)Lk);
            break;
        case 6: {                                  // dilate(cos,3) * cos
            unsigned q = (unsigned)k / 3u;
            if ((unsigned)k != 3u * q) { val = 0.0f; }
            else { int Lq = ((int)q <= CAP) ? (int)q : 0;
                   val = cosf(th * (float)Lk) * cosf(th * (float)Lq); }
        } break;
        default: {                                 // dilate(sin,2) * sin
            if (k & 1) { val = 0.0f; }
            else { int q = k >> 1; int Lq = (q <= CAP) ? q : 0;
                   val = sinf(th * (float)Lk) * sinf(th * (float)Lq); }
        } break;
        }
        if (k == 0) val -= 1.0f;                   // bake -eye into V[0]
        V[k] = val;
    }
    __syncthreads();

    // ---- stage 2: R[p][m] = {V[4m+p], V[4m+p-1], V[4m+p-2], V[4m+p-3]} ----
    const f32x4* V4 = reinterpret_cast<const f32x4*>(V);
    #pragma unroll
    for (int it = 0; it < 8; ++it) {
        const int p = it >> 1;                     // compile-time phase
        const int m = ((it & 1) << 8) + tid;       // 0..511
        f32x4 A = V4[m];
        f32x4 B = (m > 0) ? V4[m - 1] : (f32x4){0.f, 0.f, 0.f, 0.f};
        f32x4 w;
        if      (p == 0) w = (f32x4){A.x, B.w, B.z, B.y};
        else if (p == 1) w = (f32x4){A.y, A.x, B.w, B.z};
        else if (p == 2) w = (f32x4){A.z, A.y, A.x, B.w};
        else             w = (f32x4){A.w, A.z, A.y, A.x};
        R[p * 512 + m] = w;
    }
    __syncthreads();

    // ---- stage 3: store stream (1 b128 LDS read + 1 dwordx4 store per f4) ----
    f32x4* outh = out4 + (size_t)h * (T * 512);
    const f32x4 zero = {0.f, 0.f, 0.f, 0.f};
    #pragma unroll 8
    for (int k2 = 0; k2 < ROWS * 2; ++k2) {
        const int r  = k2 >> 1;
        const int c4 = ((k2 & 1) << 8) + tid;
        const int i  = row0 + r;
        const int p  = i & 3;                      // wave-uniform
        const int m  = (i >> 2) - c4;              // lane stride -1: conflict-free
        f32x4 t = R[p * 512 + ((m > 0) ? m : 0)];
        if (m < 0) t = zero;
        outh[(size_t)i * 512 + c4] = t;
    }
}

extern "C" void kernel_launch(void* const* d_in, const int* in_sizes, int n_in,
                              void* d_out, int out_size, void* d_ws, size_t ws_size,
                              hipStream_t stream) {
    (void)in_sizes; (void)n_in; (void)d_ws; (void)ws_size; (void)out_size;
    const float* eta   = (const float*)d_in[0];
    const float* nu    = (const float*)d_in[1];
    const float* theta = (const float*)d_in[2];

    dim3 grid(T / ROWS, 8, 1);   // 128 x 8 = 1024 blocks; 40 KB LDS -> 4 blocks/CU
    rem_kernel<<<grid, 256, 0, stream>>>(eta, nu, theta, (f32x4*)d_out);
}